// Round 5
// baseline (3697.203 us; speedup 1.0000x reference)
//
#include <hip/hip_runtime.h>

typedef unsigned short USHORT;
typedef __attribute__((ext_vector_type(8))) __bf16 bf16x8;
typedef __attribute__((ext_vector_type(4))) float f32x4;

#define B_   8
#define T_   2048
#define D_   1024
#define QD_  256
#define L_   4
#define M_   (B_ * T_)      // 16384
#define NCLS_ 1000
#define PI_F 3.14159265358979323846f

// ---------- helpers ----------
__device__ __forceinline__ float b2f(USHORT u) { return __uint_as_float(((unsigned)u) << 16); }
__device__ __forceinline__ USHORT f2bf(float f) {
  unsigned u = __float_as_uint(f);
  u += 0x7fffu + ((u >> 16) & 1u);  // RNE
  return (USHORT)(u >> 16);
}
// zero-out inf/nan (bit test; insurance only)
__device__ __forceinline__ float fixf(float v) {
  unsigned u = __float_as_uint(v);
  return ((u & 0x7F800000u) == 0x7F800000u) ? 0.f : v;
}
// block=256 (4 waves): reduce two values across block
__device__ __forceinline__ void breduce2(float& a, float& b, float* buf) {
#pragma unroll
  for (int off = 32; off > 0; off >>= 1) { a += __shfl_down(a, off); b += __shfl_down(b, off); }
  const int lane = threadIdx.x & 63, w = threadIdx.x >> 6;
  __syncthreads();
  if (lane == 0) { buf[w] = a; buf[4 + w] = b; }
  __syncthreads();
  a = buf[0] + buf[1] + buf[2] + buf[3];
  b = buf[4] + buf[5] + buf[6] + buf[7];
}

// ---------- weight split: f32 -> bf16 hi/lo planes (1M elements) ----------
template <bool COMP>
__global__ __launch_bounds__(256) void wsplit_k(const float* __restrict__ w,
                                                USHORT* __restrict__ hi, USHORT* __restrict__ lo) {
  const int i = (blockIdx.x * 256 + threadIdx.x) * 4;
  const float4 v = *(const float4*)(w + i);
  const float vv[4] = {v.x, v.y, v.z, v.w};
#pragma unroll
  for (int j = 0; j < 4; j++) {
    const USHORT h = f2bf(vv[j]);
    hi[i + j] = h;
    if (COMP) lo[i + j] = f2bf(vv[j] - b2f(h));
  }
}

// ---------- embed: x = embed[tokens] + pos (f32 in), store bf16 hi/lo planes ----------
template <bool COMP>
__global__ __launch_bounds__(256) void embed_k(const int* __restrict__ tok,
                                               const float* __restrict__ emb,
                                               const float* __restrict__ pos,
                                               USHORT* __restrict__ xhi, USHORT* __restrict__ xlo) {
  const int m = blockIdx.x;
  const int t = m & (T_ - 1);
  const int tk = tok[m];
  const int c = threadIdx.x * 4;
  const float* e = emb + (size_t)tk * D_ + c;
  const float* p = pos + (size_t)t * D_ + c;
  const size_t o = (size_t)m * D_ + c;
#pragma unroll
  for (int i = 0; i < 4; i++) {
    const float v = e[i] + p[i];
    const USHORT h = f2bf(v);
    xhi[o + i] = h;
    if (COMP) xlo[o + i] = f2bf(v - b2f(h));
  }
}

// ---------- GEMM: C[m][n] = sum_k x[m][k] * W[n][k] + bias[n] ----------
// x = xhi + xlo, W = Whi + Wlo (bf16 planes); computes hi*hi + hi*lo + lo*hi.
// 128x128 tile, BK=32, 4 waves of 64x64, mfma_f32_16x16x32_bf16, synchronous staging.
// A pointers chunk-local. TR: store transposed as (CHB, D, T) f32.
template <bool TR, bool COMP>
__global__ __launch_bounds__(256, 2) void gemm_k(const USHORT* __restrict__ Ahi,
                                                 const USHORT* __restrict__ Alo,
                                                 const USHORT* __restrict__ Bhi,
                                                 const USHORT* __restrict__ Blo,
                                                 const float* __restrict__ bias,
                                                 float* __restrict__ out) {
  __shared__ __align__(16) USHORT lds[16384];  // 32KB: Ahi[0,8K) Alo[8K,16K) Bhi[16K,24K) Blo[24K,32K)
  char* sbase = (char*)lds;
  const int tid = threadIdx.x;
  const int lane = tid & 63;
  const int wave = tid >> 6;
  const int wr = wave >> 1, wc = wave & 1;
  const int m0 = blockIdx.y * 128, n0 = blockIdx.x * 128;

  f32x4 acc[4][4];
#pragma unroll
  for (int i = 0; i < 4; i++)
#pragma unroll
    for (int j = 0; j < 4; j++) acc[i][j] = (f32x4){0.f, 0.f, 0.f, 0.f};

  const int lrow = tid >> 2;            // 0..63
  const int lcolb = (tid & 3) * 16;     // bytes within 64B k-row
  const char* gah = (const char*)Ahi + (size_t)(m0 + lrow) * 2048 + lcolb;
  const char* gal = (const char*)Alo + (size_t)(m0 + lrow) * 2048 + lcolb;
  const char* gbh = (const char*)Bhi + (size_t)(n0 + lrow) * 2048 + lcolb;
  const char* gbl = (const char*)Blo + (size_t)(n0 + lrow) * 2048 + lcolb;
  char* s0 = sbase + tid * 16;

  const int koff = (lane >> 4) * 16;                 // byte k-offset of fragment
  const int mA = (wr * 64 + (lane & 15)) * 64;       // byte row base (A)
  const int nB = (wc * 64 + (lane & 15)) * 64;       // byte row base (B)

  for (int kk = 0; kk < 1024; kk += 32) {
    const uint4 vah0 = *(const uint4*)gah;
    const uint4 vah1 = *(const uint4*)(gah + 64 * 2048);
    const uint4 vbh0 = *(const uint4*)gbh;
    const uint4 vbh1 = *(const uint4*)(gbh + 64 * 2048);
    uint4 val0, val1, vbl0, vbl1;
    if (COMP) {
      val0 = *(const uint4*)gal; val1 = *(const uint4*)(gal + 64 * 2048);
      vbl0 = *(const uint4*)gbl; vbl1 = *(const uint4*)(gbl + 64 * 2048);
    }
    gah += 64; gal += 64; gbh += 64; gbl += 64;
    __syncthreads();                    // all waves done reading previous tile
    *(uint4*)(s0)         = vah0;
    *(uint4*)(s0 + 4096)  = vah1;
    *(uint4*)(s0 + 16384) = vbh0;
    *(uint4*)(s0 + 20480) = vbh1;
    if (COMP) {
      *(uint4*)(s0 + 8192)  = val0;
      *(uint4*)(s0 + 12288) = val1;
      *(uint4*)(s0 + 24576) = vbl0;
      *(uint4*)(s0 + 28672) = vbl1;
    }
    __syncthreads();                    // staging visible to all waves
    bf16x8 ah[4], al[4], bh[4], bl[4];
#pragma unroll
    for (int i = 0; i < 4; i++) {
      const char* pa = sbase + mA + i * 1024 + koff;
      ah[i] = *(const bf16x8*)pa;
      if (COMP) al[i] = *(const bf16x8*)(pa + 8192);
    }
#pragma unroll
    for (int j = 0; j < 4; j++) {
      const char* pb = sbase + 16384 + nB + j * 1024 + koff;
      bh[j] = *(const bf16x8*)pb;
      if (COMP) bl[j] = *(const bf16x8*)(pb + 8192);
    }
#pragma unroll
    for (int i = 0; i < 4; i++)
#pragma unroll
      for (int j = 0; j < 4; j++) {
        acc[i][j] = __builtin_amdgcn_mfma_f32_16x16x32_bf16(ah[i], bh[j], acc[i][j], 0, 0, 0);
        if (COMP) {
          acc[i][j] = __builtin_amdgcn_mfma_f32_16x16x32_bf16(ah[i], bl[j], acc[i][j], 0, 0, 0);
          acc[i][j] = __builtin_amdgcn_mfma_f32_16x16x32_bf16(al[i], bh[j], acc[i][j], 0, 0, 0);
        }
      }
  }

#pragma unroll
  for (int j = 0; j < 4; j++) {
    const int n = n0 + wc * 64 + j * 16 + (lane & 15);
    const float bv = bias[n];
#pragma unroll
    for (int i = 0; i < 4; i++) {
      const int mb = m0 + wr * 64 + i * 16 + ((lane >> 4) << 2);
#pragma unroll
      for (int r = 0; r < 4; r++) {
        const int m = mb + r;                  // chunk-local row
        const float v = acc[i][j][r] + bv;
        if (TR) {
          const int lb = m >> 11, t = m & (T_ - 1);  // local batch, time
          out[(((size_t)lb << 10) + n) * T_ + t] = v;
        } else {
          out[(size_t)m * D_ + n] = v;
        }
      }
    }
  }
}

// ---------- FFT + spectral filter + IFFT over one (local batch, channel) sequence ----------
__device__ void fft_core(float* re, float* im, const float* twr, const float* twi, int tid, bool inv) {
  int lh = 0;
  for (int half = 1; half < T_; half <<= 1, lh++) {
    const int step = (T_ / 2) >> lh;
    for (int j = tid; j < T_ / 2; j += 256) {
      const int k = j & (half - 1);
      const int g = j >> lh;
      const int idx = (g << (lh + 1)) + k;
      float wr = twr[k * step];
      float wi = twi[k * step];
      if (inv) wi = -wi;
      const float vr = re[idx + half], vi = im[idx + half];
      const float tr = vr * wr - vi * wi;
      const float ti = vr * wi + vi * wr;
      const float ur = re[idx], ui = im[idx];
      re[idx] = ur + tr;        im[idx] = ui + ti;
      re[idx + half] = ur - tr; im[idx + half] = ui - ti;
    }
    __syncthreads();
  }
}

// C = FFT(q + i r); Qs,Rs by Hermitian split; z = Qs conj(Rs) e^{i(pq-pr)}; inter = Re(IFFT(z)) -> QT
__global__ __launch_bounds__(256) void fft_spectral_k(float* __restrict__ QT,
                                                      const float* __restrict__ RT,
                                                      const float* __restrict__ alpha) {
  __shared__ float re[T_], im[T_], twr[T_ / 2], twi[T_ / 2];
  const int tid = threadIdx.x;
  const int seq = blockIdx.x;  // lb*D + n
  const float av = alpha[seq & (QD_ - 1)];
  float* q = QT + (size_t)seq * T_;
  const float* r = RT + (size_t)seq * T_;

  for (int j = tid; j < T_ / 2; j += 256) {
    float s, c;
    sincosf(-PI_F * (float)j * (1.0f / 1024.0f), &s, &c);  // e^{-2pi i j / 2048}
    twr[j] = c; twi[j] = s;
  }
  for (int t = tid; t < T_; t += 256) {
    const int p = __brev((unsigned)t) >> 21;  // 11-bit reversal
    re[p] = q[t];
    im[p] = r[t];
  }
  __syncthreads();
  fft_core(re, im, twr, twi, tid, false);

  // two-phase spectral filter: compute all pair results into registers, barrier, write.
  float zfr[5], zfi[5], zcr[5], zci[5];
  int cnt = 0;
  for (int f = tid; f <= T_ / 2; f += 256) {
    const int fc = (T_ - f) & (T_ - 1);
    const float ar = re[f], ai = im[f];
    const float br = re[fc], bi = im[fc];
    const float qr = 0.5f * (ar + br), qi = 0.5f * (ai - bi);   // Qs[f]
    const float rr = 0.5f * (ai + bi), ri = -0.5f * (ar - br);  // Rs[f]
    const float qmag = sqrtf(qr * qr + qi * qi);
    const float rmag = sqrtf(rr * rr + ri * ri);
    const float ph = av * (atanf(logf(qmag + 1e-8f)) - atanf(logf(rmag + 1e-8f)));
    float sp, cp;
    sincosf(ph, &sp, &cp);
    const float mr = qr * rr + qi * ri;   // Re(Qs conj(Rs))
    const float mi = qi * rr - qr * ri;   // Im(Qs conj(Rs))
    zfr[cnt] = mr * cp - mi * sp;
    zfi[cnt] = mr * sp + mi * cp;
    zcr[cnt] = mr * cp + mi * sp;         // z[fc] = conj(M) e^{i ph}
    zci[cnt] = mr * sp - mi * cp;
    cnt++;
  }
  __syncthreads();
  cnt = 0;
  for (int f = tid; f <= T_ / 2; f += 256) {
    const int fc = (T_ - f) & (T_ - 1);
    re[f] = zfr[cnt]; im[f] = zfi[cnt];
    if (fc != f) { re[fc] = zcr[cnt]; im[fc] = zci[cnt]; }
    cnt++;
  }
  __syncthreads();
  for (int t = tid; t < T_; t += 256) {   // bit-reverse permute for the IFFT
    const int p = __brev((unsigned)t) >> 21;
    if (t < p) {
      float a = re[t]; re[t] = re[p]; re[p] = a;
      a = im[t]; im[t] = im[p]; im[p] = a;
    }
  }
  __syncthreads();
  fft_core(re, im, twr, twi, tid, true);
  for (int t = tid; t < T_; t += 256) q[t] = re[t] * (1.0f / (float)T_);
}

// ---------- (CHB, D, T) -> (CHB*T, D) transpose ----------
__global__ __launch_bounds__(256) void transpose_k(const float* __restrict__ src, float* __restrict__ dst) {
  __shared__ float tile[32][33];
  const int lb = blockIdx.z;
  const int n0 = blockIdx.y * 32;
  const int t0 = blockIdx.x * 32;
  const int tx = threadIdx.x, ty = threadIdx.y;
#pragma unroll
  for (int r = 0; r < 4; r++)
    tile[ty + r * 8][tx] = src[((size_t)lb * D_ + n0 + ty + r * 8) * T_ + t0 + tx];
  __syncthreads();
#pragma unroll
  for (int r = 0; r < 4; r++)
    dst[((size_t)lb * T_ + t0 + ty + r * 8) * D_ + n0 + tx] = tile[tx][ty + r * 8];
}

// ---------- hamilton + sp_ln + gate + rot + residual + out_ln; updates x planes ----------
// All params f32. inter/Hb chunk-local; xhi/xlo pre-offset to chunk base.
template <bool COMP>
__global__ __launch_bounds__(256) void fused_k(const float* __restrict__ inter, const float* __restrict__ Hb,
                                               const float* __restrict__ spw, const float* __restrict__ spb,
                                               const float* __restrict__ gate, const float* __restrict__ rot,
                                               const float* __restrict__ ow, const float* __restrict__ ob,
                                               USHORT* xhi, USHORT* xlo) {
  __shared__ float red[8];
  const int m = blockIdx.x;
  const int d = threadIdx.x;
  const size_t base = (size_t)m * D_;
  float iv[4], hv[4];
#pragma unroll
  for (int k = 0; k < 4; k++) {
    iv[k] = fixf(inter[base + k * 256 + d]);
    hv[k] = fixf(Hb[base + k * 256 + d]);
  }
  float o[4];
  o[0] = iv[0] * hv[0] - iv[1] * hv[1] - iv[2] * hv[2] - iv[3] * hv[3];
  o[1] = iv[0] * hv[1] + iv[1] * hv[0] + iv[2] * hv[3] - iv[3] * hv[2];
  o[2] = iv[0] * hv[2] - iv[1] * hv[3] + iv[2] * hv[0] + iv[3] * hv[1];
  o[3] = iv[0] * hv[3] + iv[1] * hv[2] - iv[2] * hv[1] + iv[3] * hv[0];
  float s = o[0] + o[1] + o[2] + o[3];
  float ss = o[0] * o[0] + o[1] * o[1] + o[2] * o[2] + o[3] * o[3];
  breduce2(s, ss, red);
  const float mean = s * (1.0f / 1024.0f);
  const float rstd = rsqrtf(ss * (1.0f / 1024.0f) - mean * mean + 1e-5f);
  const float g = gate[d];
  float xf[4];
#pragma unroll
  for (int k = 0; k < 4; k++)
    xf[k] = ((o[k] - mean) * rstd * spw[k * 256 + d] + spb[k * 256 + d]) * g;
  float y[4];
#pragma unroll
  for (int j = 0; j < 4; j++) {
    float a = 0.f;
#pragma unroll
    for (int k = 0; k < 4; k++) a += rot[j * 4 + k] * xf[k];
    const size_t idx = base + j * 256 + d;
    float res = b2f(xhi[idx]);
    if (COMP) res += b2f(xlo[idx]);
    y[j] = a + res;  // + residual
  }
  float s2 = y[0] + y[1] + y[2] + y[3];
  float ss2 = y[0] * y[0] + y[1] * y[1] + y[2] * y[2] + y[3] * y[3];
  breduce2(s2, ss2, red);
  const float mean2 = s2 * (1.0f / 1024.0f);
  const float rstd2 = rsqrtf(ss2 * (1.0f / 1024.0f) - mean2 * mean2 + 1e-5f);
#pragma unroll
  for (int j = 0; j < 4; j++) {
    const float v = (y[j] - mean2) * rstd2 * ow[j * 256 + d] + ob[j * 256 + d];
    const size_t idx = base + j * 256 + d;
    const USHORT hh = f2bf(v);
    xhi[idx] = hh;
    if (COMP) xlo[idx] = f2bf(v - b2f(hh));
  }
}

// ---------- mean over T (partials + atomics; pooled must be zeroed) ----------
template <bool COMP>
__global__ __launch_bounds__(256) void pool_k(const USHORT* __restrict__ xhi, const USHORT* __restrict__ xlo,
                                              float* __restrict__ pooled) {
  const int b = blockIdx.z;
  const int d = blockIdx.x * 256 + threadIdx.x;
  const int t0 = blockIdx.y * 256;
  float s = 0.f;
  for (int t = t0; t < t0 + 256; t++) {
    const size_t idx = ((size_t)(b * T_ + t)) * D_ + d;
    s += b2f(xhi[idx]);
    if (COMP) s += b2f(xlo[idx]);
  }
  atomicAdd(&pooled[b * D_ + d], s);
}

// ---------- classifier LN (f32 params) ----------
__global__ __launch_bounds__(256) void clsln_k(const float* __restrict__ pooled, const float* __restrict__ w,
                                               const float* __restrict__ bias, float* __restrict__ h) {
  __shared__ float red[8];
  const int b = blockIdx.x;
  const int d = threadIdx.x;
  float v[4];
#pragma unroll
  for (int j = 0; j < 4; j++) v[j] = fixf(pooled[b * D_ + j * 256 + d]) * (1.0f / (float)T_);
  float s = v[0] + v[1] + v[2] + v[3];
  float ss = v[0] * v[0] + v[1] * v[1] + v[2] * v[2] + v[3] * v[3];
  breduce2(s, ss, red);
  const float mean = s * (1.0f / (float)D_);
  const float rstd = rsqrtf(ss * (1.0f / (float)D_) - mean * mean + 1e-5f);
#pragma unroll
  for (int j = 0; j < 4; j++)
    h[b * D_ + j * 256 + d] = (v[j] - mean) * rstd * w[j * 256 + d] + bias[j * 256 + d];
}

// ---------- classifier GEMM: one wave per (b, n); f32 in/out ----------
__global__ __launch_bounds__(256) void cls_k(const float* __restrict__ h, const float* __restrict__ W,
                                             const float* __restrict__ cb, float* __restrict__ out) {
  const int wv = blockIdx.x * 4 + (threadIdx.x >> 6);
  const int lane = threadIdx.x & 63;
  const int b = wv / NCLS_;
  const int n = wv - b * NCLS_;
  const float* hb = h + b * D_;
  const float* wr = W + (size_t)n * D_;
  float s = 0.f;
  for (int j = lane; j < D_; j += 64) s += hb[j] * wr[j];
#pragma unroll
  for (int off = 32; off > 0; off >>= 1) s += __shfl_down(s, off);
  if (lane == 0) out[b * NCLS_ + n] = fixf(s + cb[n]);
}

// ---------- launch ----------
extern "C" void kernel_launch(void* const* d_in, const int* in_sizes, int n_in,
                              void* d_out, int out_size, void* d_ws, size_t ws_size,
                              hipStream_t stream) {
  (void)in_sizes; (void)n_in; (void)out_size;
  const int* tokens = (const int*)d_in[0];
  const float* emb = (const float*)d_in[1];
  const float* pos = (const float*)d_in[2];
  const float* Wq = (const float*)d_in[3];
  const float* bq = (const float*)d_in[4];
  const float* Wr = (const float*)d_in[5];
  const float* br = (const float*)d_in[6];
  const float* Wh = (const float*)d_in[7];
  const float* bh = (const float*)d_in[8];
  const float* alpha = (const float*)d_in[9];
  const float* spw = (const float*)d_in[10];
  const float* spb = (const float*)d_in[11];
  const float* gate = (const float*)d_in[12];
  const float* rot = (const float*)d_in[13];
  const float* outw = (const float*)d_in[14];
  const float* outb = (const float*)d_in[15];
  const float* clw = (const float*)d_in[16];
  const float* clb = (const float*)d_in[17];
  const float* clsW = (const float*)d_in[18];
  const float* clsb = (const float*)d_in[19];
  float* out = (float*)d_out;

  // ---- adaptive footprint from ws_size ----
  const size_t MB = 1048576;
  int CHB; bool comp;
  if      (ws_size >= 172 * MB) { CHB = 4; comp = true;  }   // 64+12+96
  else if (ws_size >= 124 * MB) { CHB = 2; comp = true;  }   // 64+12+48
  else if (ws_size >= 100 * MB) { CHB = 1; comp = true;  }   // 64+12+24
  else                          { CHB = 1; comp = false; }   // 32+6+24 = 62
  const int nchunks = B_ / CHB;
  const int chm = CHB * T_;
  const size_t chunkf = (size_t)CHB * T_ * D_ * 4;

  char* ws = (char*)d_ws;
  USHORT* xhi = (USHORT*)ws;                                    // 32 MB
  USHORT* xlo = (USHORT*)(ws + 32 * MB);                        // 32 MB (comp only)
  char* wb = ws + (comp ? 64 : 32) * MB;
  USHORT* Whi = (USHORT*)wb;                                    // 6 MB: Q,R,H hi planes
  USHORT* Wlo = (USHORT*)(wb + 6 * MB);                         // 6 MB (comp only)
  char* fb = wb + (comp ? 12 : 6) * MB;
  float* QTc = (float*)fb;
  float* RTc = (float*)(fb + chunkf);
  float* Hc  = (float*)(fb + 2 * chunkf);
  float* pooled = (float*)fb;                                   // reuse after layers
  float* hbuf   = (float*)(fb + 32768);

  if (comp) embed_k<true><<<M_, 256, 0, stream>>>(tokens, emb, pos, xhi, xlo);
  else      embed_k<false><<<M_, 256, 0, stream>>>(tokens, emb, pos, xhi, xlo);

  const int DD = D_ * D_;
  const dim3 gemm_grid(8, chm / 128);
  const dim3 tr_grid(T_ / 32, D_ / 32, CHB);
  const dim3 tr_blk(32, 8);
  for (int l = 0; l < L_; l++) {
    const size_t wo = (size_t)l * DD;
    // split this layer's weights into bf16 planes
    if (comp) {
      wsplit_k<true><<<DD / 1024, 256, 0, stream>>>(Wq + wo, Whi, Wlo);
      wsplit_k<true><<<DD / 1024, 256, 0, stream>>>(Wr + wo, Whi + DD, Wlo + DD);
      wsplit_k<true><<<DD / 1024, 256, 0, stream>>>(Wh + wo, Whi + 2 * DD, Wlo + 2 * DD);
    } else {
      wsplit_k<false><<<DD / 1024, 256, 0, stream>>>(Wq + wo, Whi, Wlo);
      wsplit_k<false><<<DD / 1024, 256, 0, stream>>>(Wr + wo, Whi + DD, Wlo + DD);
      wsplit_k<false><<<DD / 1024, 256, 0, stream>>>(Wh + wo, Whi + 2 * DD, Wlo + 2 * DD);
    }
    for (int c = 0; c < nchunks; c++) {
      const size_t xoff = (size_t)c * chm * D_;
      const USHORT* xh = xhi + xoff;
      const USHORT* xl = xlo + xoff;
      if (comp) {
        gemm_k<true, true><<<gemm_grid, 256, 0, stream>>>(xh, xl, Whi, Wlo, bq + l * D_, QTc);
        gemm_k<true, true><<<gemm_grid, 256, 0, stream>>>(xh, xl, Whi + DD, Wlo + DD, br + l * D_, RTc);
        gemm_k<false, true><<<gemm_grid, 256, 0, stream>>>(xh, xl, Whi + 2 * DD, Wlo + 2 * DD, bh + l * D_, Hc);
      } else {
        gemm_k<true, false><<<gemm_grid, 256, 0, stream>>>(xh, xh, Whi, Whi, bq + l * D_, QTc);
        gemm_k<true, false><<<gemm_grid, 256, 0, stream>>>(xh, xh, Whi + DD, Whi + DD, br + l * D_, RTc);
        gemm_k<false, false><<<gemm_grid, 256, 0, stream>>>(xh, xh, Whi + 2 * DD, Whi + 2 * DD, bh + l * D_, Hc);
      }
      fft_spectral_k<<<CHB * D_, 256, 0, stream>>>(QTc, RTc, alpha + l * QD_);
      transpose_k<<<tr_grid, tr_blk, 0, stream>>>(QTc, RTc);  // inter -> (chm, D) in RTc
      if (comp)
        fused_k<true><<<chm, 256, 0, stream>>>(RTc, Hc, spw + l * D_, spb + l * D_, gate + l * QD_,
                                               rot + l * 16, outw + l * D_, outb + l * D_,
                                               xhi + xoff, xlo + xoff);
      else
        fused_k<false><<<chm, 256, 0, stream>>>(RTc, Hc, spw + l * D_, spb + l * D_, gate + l * QD_,
                                                rot + l * 16, outw + l * D_, outb + l * D_,
                                                xhi + xoff, xlo + xoff);
    }
  }

  hipMemsetAsync(pooled, 0, B_ * D_ * sizeof(float), stream);
  if (comp) pool_k<true><<<dim3(4, 8, 8), 256, 0, stream>>>(xhi, xlo, pooled);
  else      pool_k<false><<<dim3(4, 8, 8), 256, 0, stream>>>(xhi, xlo, pooled);
  clsln_k<<<B_, 256, 0, stream>>>(pooled, clw, clb, hbuf);
  cls_k<<<(B_ * NCLS_) / 4, 256, 0, stream>>>(hbuf, clsW, clsb, out);
}

// Round 6
// 2552.461 us; speedup vs baseline: 1.4485x; 1.4485x over previous
//
#include <hip/hip_runtime.h>

typedef unsigned short USHORT;
typedef __attribute__((ext_vector_type(8))) __bf16 bf16x8;
typedef __attribute__((ext_vector_type(4))) float f32x4;

#define B_   8
#define T_   2048
#define D_   1024
#define QD_  256
#define L_   4
#define M_   (B_ * T_)      // 16384
#define NCLS_ 1000
#define PI_F 3.14159265358979323846f
// skewed LDS addressing: one pad word per 32 — breaks power-of-2 stride conflicts
#define IX(a) ((a) + ((a) >> 5))

// ---------- helpers ----------
__device__ __forceinline__ float b2f(USHORT u) { return __uint_as_float(((unsigned)u) << 16); }
__device__ __forceinline__ USHORT f2bf(float f) {
  unsigned u = __float_as_uint(f);
  u += 0x7fffu + ((u >> 16) & 1u);  // RNE
  return (USHORT)(u >> 16);
}
__device__ __forceinline__ float fixf(float v) {
  unsigned u = __float_as_uint(v);
  return ((u & 0x7F800000u) == 0x7F800000u) ? 0.f : v;
}
__device__ __forceinline__ void glds16(const void* g, void* l) {
  __builtin_amdgcn_global_load_lds((const __attribute__((address_space(1))) void*)g,
                                   (__attribute__((address_space(3))) void*)l, 16, 0, 0);
}
// digit-reversal for radix sequence [4,4,4,4,4,2]: position of frequency k after DIF
__device__ __forceinline__ int dr_pos(int k) {
  return ((k & 3) << 9) | (((k >> 2) & 3) << 7) | (((k >> 4) & 3) << 5)
       | (((k >> 6) & 3) << 3) | (((k >> 8) & 3) << 1) | (k >> 10);
}
// block=256 (4 waves): reduce two values across block
__device__ __forceinline__ void breduce2(float& a, float& b, float* buf) {
#pragma unroll
  for (int off = 32; off > 0; off >>= 1) { a += __shfl_down(a, off); b += __shfl_down(b, off); }
  const int lane = threadIdx.x & 63, w = threadIdx.x >> 6;
  __syncthreads();
  if (lane == 0) { buf[w] = a; buf[4 + w] = b; }
  __syncthreads();
  a = buf[0] + buf[1] + buf[2] + buf[3];
  b = buf[4] + buf[5] + buf[6] + buf[7];
}

// ---------- weight split: f32 -> bf16 hi/lo planes ----------
template <bool COMP>
__global__ __launch_bounds__(256) void wsplit_k(const float* __restrict__ w,
                                                USHORT* __restrict__ hi, USHORT* __restrict__ lo) {
  const int i = (blockIdx.x * 256 + threadIdx.x) * 4;
  const float4 v = *(const float4*)(w + i);
  const float vv[4] = {v.x, v.y, v.z, v.w};
#pragma unroll
  for (int j = 0; j < 4; j++) {
    const USHORT h = f2bf(vv[j]);
    hi[i + j] = h;
    if (COMP) lo[i + j] = f2bf(vv[j] - b2f(h));
  }
}

// ---------- embed: x = embed[tokens] + pos (f32 in), store bf16 hi/lo planes ----------
template <bool COMP>
__global__ __launch_bounds__(256) void embed_k(const int* __restrict__ tok,
                                               const float* __restrict__ emb,
                                               const float* __restrict__ pos,
                                               USHORT* __restrict__ xhi, USHORT* __restrict__ xlo) {
  const int m = blockIdx.x;
  const int t = m & (T_ - 1);
  const int tk = tok[m];
  const int c = threadIdx.x * 4;
  const float* e = emb + (size_t)tk * D_ + c;
  const float* p = pos + (size_t)t * D_ + c;
  const size_t o = (size_t)m * D_ + c;
#pragma unroll
  for (int i = 0; i < 4; i++) {
    const float v = e[i] + p[i];
    const USHORT h = f2bf(v);
    xhi[o + i] = h;
    if (COMP) xlo[o + i] = f2bf(v - b2f(h));
  }
}

// ---------- GEMM: C[m][n] = sum_k x[m][k] * W[n][k] + bias[n] ----------
// x = xhi+xlo, W = Whi+Wlo bf16 planes; hi*hi + hi*lo + lo*hi (COMP).
// 128x128 tile, BK=32, 4 waves of 64x64, mfma_f32_16x16x32_bf16, async global_load_lds (m97 shape).
template <bool TR, bool COMP>
__global__ __launch_bounds__(256, 2) void gemm_k(const USHORT* __restrict__ Ahi,
                                                 const USHORT* __restrict__ Alo,
                                                 const USHORT* __restrict__ Bhi,
                                                 const USHORT* __restrict__ Blo,
                                                 const float* __restrict__ bias,
                                                 float* __restrict__ out) {
  __shared__ __align__(16) USHORT lds[16384];  // 32KB: Ahi[0,8K) Alo[8K,16K) Bhi[16K,24K) Blo[24K,32K)
  char* sbase = (char*)lds;
  const int tid = threadIdx.x;
  const int lane = tid & 63;
  const int wave = tid >> 6;
  const int wr = wave >> 1, wc = wave & 1;
  const int m0 = blockIdx.y * 128, n0 = blockIdx.x * 128;

  f32x4 acc[4][4];
#pragma unroll
  for (int i = 0; i < 4; i++)
#pragma unroll
    for (int j = 0; j < 4; j++) acc[i][j] = (f32x4){0.f, 0.f, 0.f, 0.f};

  const int lrow = tid >> 2;            // 0..63
  const int lcolb = (tid & 3) * 16;     // bytes within 64B k-row
  const char* gah = (const char*)Ahi + (size_t)(m0 + lrow) * 2048 + lcolb;
  const char* gal = (const char*)Alo + (size_t)(m0 + lrow) * 2048 + lcolb;
  const char* gbh = (const char*)Bhi + (size_t)(n0 + lrow) * 2048 + lcolb;
  const char* gbl = (const char*)Blo + (size_t)(n0 + lrow) * 2048 + lcolb;
  char* s0 = sbase + tid * 16;          // wave-uniform base + lane*16 per wave ✓

  const int koff = (lane >> 4) * 16;                 // byte k-offset of fragment
  const int mA = (wr * 64 + (lane & 15)) * 64;       // byte row base (A)
  const int nB = (wc * 64 + (lane & 15)) * 64;       // byte row base (B)

  for (int kk = 0; kk < 1024; kk += 32) {
    __syncthreads();                    // consumers of previous tile done
    glds16(gah, s0);
    glds16(gah + 64 * 2048, s0 + 4096);
    if (COMP) {
      glds16(gal, s0 + 8192);
      glds16(gal + 64 * 2048, s0 + 12288);
    }
    glds16(gbh, s0 + 16384);
    glds16(gbh + 64 * 2048, s0 + 20480);
    if (COMP) {
      glds16(gbl, s0 + 24576);
      glds16(gbl + 64 * 2048, s0 + 28672);
    }
    gah += 64; gal += 64; gbh += 64; gbl += 64;
    __syncthreads();                    // vmcnt drained by compiler before barrier
    bf16x8 ah[4], al[4], bh[4], bl[4];
#pragma unroll
    for (int i = 0; i < 4; i++) {
      const char* pa = sbase + mA + i * 1024 + koff;
      ah[i] = *(const bf16x8*)pa;
      if (COMP) al[i] = *(const bf16x8*)(pa + 8192);
    }
#pragma unroll
    for (int j = 0; j < 4; j++) {
      const char* pb = sbase + 16384 + nB + j * 1024 + koff;
      bh[j] = *(const bf16x8*)pb;
      if (COMP) bl[j] = *(const bf16x8*)(pb + 8192);
    }
#pragma unroll
    for (int i = 0; i < 4; i++)
#pragma unroll
      for (int j = 0; j < 4; j++) {
        acc[i][j] = __builtin_amdgcn_mfma_f32_16x16x32_bf16(ah[i], bh[j], acc[i][j], 0, 0, 0);
        if (COMP) {
          acc[i][j] = __builtin_amdgcn_mfma_f32_16x16x32_bf16(ah[i], bl[j], acc[i][j], 0, 0, 0);
          acc[i][j] = __builtin_amdgcn_mfma_f32_16x16x32_bf16(al[i], bh[j], acc[i][j], 0, 0, 0);
        }
      }
  }

#pragma unroll
  for (int j = 0; j < 4; j++) {
    const int n = n0 + wc * 64 + j * 16 + (lane & 15);
    const float bv = bias[n];
#pragma unroll
    for (int i = 0; i < 4; i++) {
      const int mb = m0 + wr * 64 + i * 16 + ((lane >> 4) << 2);
#pragma unroll
      for (int r = 0; r < 4; r++) {
        const int m = mb + r;                  // chunk-local row
        const float v = acc[i][j][r] + bv;
        if (TR) {
          const int lb = m >> 11, t = m & (T_ - 1);  // local batch, time
          out[(((size_t)lb << 10) + n) * T_ + t] = v;
        } else {
          out[(size_t)m * D_ + n] = v;
        }
      }
    }
  }
}

// ---------- fused FFT + spectral filter + IFFT, radix-4, digit-reversed midpoint ----------
// Forward DIF (natural -> digit-rev), filter at dr_pos(f), inverse DIT (digit-rev -> natural).
__global__ __launch_bounds__(256) void fft_spectral_k(float* __restrict__ QT,
                                                      const float* __restrict__ RT,
                                                      const float* __restrict__ alpha) {
  __shared__ float re[2112], im[2112], twr[1056], twi[1056];  // skewed: 2048+64, 1024+32
  const int tid = threadIdx.x;
  const int seq = blockIdx.x;  // lb*D + n
  const float av = alpha[seq & (QD_ - 1)];
  float* q = QT + (size_t)seq * T_;
  const float* r = RT + (size_t)seq * T_;

  for (int j = tid; j < 1024; j += 256) {
    float s, c;
    sincosf(-PI_F * (float)j * (1.0f / 1024.0f), &s, &c);  // W_2048^j
    twr[IX(j)] = c; twi[IX(j)] = s;
  }
  for (int t = tid; t < T_; t += 256) {  // natural-order load (coalesced)
    re[IX(t)] = q[t];
    im[IX(t)] = r[t];
  }
  __syncthreads();

  // ---- forward: 5 radix-4 DIF stages (S = 512,128,32,8,2) ----
#pragma unroll
  for (int s = 0; s < 5; s++) {
    const int l = 9 - 2 * s;  // log2 S
    const int S = 1 << l;
#pragma unroll
    for (int uu = 0; uu < 2; uu++) {
      const int u = tid + uu * 256;
      const int j = u & (S - 1);
      const int base = ((u >> l) << (l + 2)) | j;
      const int i0 = IX(base), i1 = IX(base + S), i2 = IX(base + 2 * S), i3 = IX(base + 3 * S);
      const int t1 = j << (2 * s);
      const float w1r = twr[IX(t1)], w1i = twi[IX(t1)];
      const float w2r = twr[IX(2 * t1)], w2i = twi[IX(2 * t1)];
      const float w3r = w1r * w2r - w1i * w2i, w3i = w1r * w2i + w1i * w2r;
      const float r0 = re[i0], q0 = im[i0], r1 = re[i1], q1 = im[i1];
      const float r2 = re[i2], q2 = im[i2], r3 = re[i3], q3 = im[i3];
      const float ar = r0 + r2, ai = q0 + q2, br = r0 - r2, bi = q0 - q2;
      const float cr = r1 + r3, ci = q1 + q3, pr = r1 - r3, pi = q1 - q3;  // d = p
      re[i0] = ar + cr; im[i0] = ai + ci;
      const float er = ar - cr, ei = ai - ci;                 // (a-c) * w2
      re[i2] = er * w2r - ei * w2i; im[i2] = er * w2i + ei * w2r;
      const float gr = br + pi, gi = bi - pr;                 // (b - i d) * w1
      re[i1] = gr * w1r - gi * w1i; im[i1] = gr * w1i + gi * w1r;
      const float hr = br - pi, hi = bi + pr;                 // (b + i d) * w3
      re[i3] = hr * w3r - hi * w3i; im[i3] = hr * w3i + hi * w3r;
    }
    __syncthreads();
  }
  // ---- forward: final radix-2 stage (span 1, no twiddle) ----
#pragma unroll
  for (int uu = 0; uu < 4; uu++) {
    const int u = tid + uu * 256;
    const int i0 = IX(2 * u), i1 = IX(2 * u + 1);
    const float r0 = re[i0], q0 = im[i0], r1 = re[i1], q1 = im[i1];
    re[i0] = r0 + r1; im[i0] = q0 + q1;
    re[i1] = r0 - r1; im[i1] = q0 - q1;
  }
  __syncthreads();

  // ---- spectral filter in digit-reversed domain (pair positions thread-owned) ----
  for (int f = tid; f <= 1024; f += 256) {
    const int fc = (2048 - f) & 2047;
    const int pf = IX(dr_pos(f)), pc = IX(dr_pos(fc));
    const float ar = re[pf], ai = im[pf];
    const float br = re[pc], bi = im[pc];
    const float qr = 0.5f * (ar + br), qi = 0.5f * (ai - bi);   // Qs[f]
    const float rr = 0.5f * (ai + bi), ri = -0.5f * (ar - br);  // Rs[f]
    const float qmag = sqrtf(qr * qr + qi * qi);
    const float rmag = sqrtf(rr * rr + ri * ri);
    const float ph = av * (atanf(logf(qmag + 1e-8f)) - atanf(logf(rmag + 1e-8f)));
    float sp, cp;
    sincosf(ph, &sp, &cp);
    const float mr = qr * rr + qi * ri;   // Re(Qs conj(Rs))
    const float mi = qi * rr - qr * ri;   // Im(Qs conj(Rs))
    re[pf] = mr * cp - mi * sp;
    im[pf] = mr * sp + mi * cp;
    if (pc != pf) {                       // z[fc] = conj(M) e^{i ph}
      re[pc] = mr * cp + mi * sp;
      im[pc] = mr * sp - mi * cp;
    }
  }
  __syncthreads();

  // ---- inverse: radix-2 first (span 1) ----
#pragma unroll
  for (int uu = 0; uu < 4; uu++) {
    const int u = tid + uu * 256;
    const int i0 = IX(2 * u), i1 = IX(2 * u + 1);
    const float r0 = re[i0], q0 = im[i0], r1 = re[i1], q1 = im[i1];
    re[i0] = r0 + r1; im[i0] = q0 + q1;
    re[i1] = r0 - r1; im[i1] = q0 - q1;
  }
  __syncthreads();
  // ---- inverse: 5 radix-4 DIT stages (S = 2,8,32,128,512), conj twiddles ----
#pragma unroll
  for (int s = 4; s >= 0; s--) {
    const int l = 9 - 2 * s;
    const int S = 1 << l;
#pragma unroll
    for (int uu = 0; uu < 2; uu++) {
      const int u = tid + uu * 256;
      const int j = u & (S - 1);
      const int base = ((u >> l) << (l + 2)) | j;
      const int i0 = IX(base), i1 = IX(base + S), i2 = IX(base + 2 * S), i3 = IX(base + 3 * S);
      const int t1 = j << (2 * s);
      const float w1r = twr[IX(t1)], w1i = twi[IX(t1)];
      const float w2r = twr[IX(2 * t1)], w2i = twi[IX(2 * t1)];
      const float w3r = w1r * w2r - w1i * w2i, w3i = w1r * w2i + w1i * w2r;
      const float r0 = re[i0], q0 = im[i0], r1 = re[i1], q1 = im[i1];
      const float r2 = re[i2], q2 = im[i2], r3 = re[i3], q3 = im[i3];
      // z_k * conj(w_k)
      const float z1r = r1 * w1r + q1 * w1i, z1i = q1 * w1r - r1 * w1i;
      const float z2r = r2 * w2r + q2 * w2i, z2i = q2 * w2r - r2 * w2i;
      const float z3r = r3 * w3r + q3 * w3i, z3i = q3 * w3r - r3 * w3i;
      const float ar = r0 + z2r, ai = q0 + z2i, br = r0 - z2r, bi = q0 - z2i;
      const float cr = z1r + z3r, ci = z1i + z3i, pr = z1r - z3r, pi = z1i - z3i;
      re[i0] = ar + cr; im[i0] = ai + ci;
      re[i2] = ar - cr; im[i2] = ai - ci;
      re[i1] = br - pi; im[i1] = bi + pr;   // b + i d
      re[i3] = br + pi; im[i3] = bi - pr;   // b - i d
    }
    __syncthreads();
  }
  for (int t = tid; t < T_; t += 256) q[t] = re[IX(t)] * (1.0f / 2048.0f);
}

// ---------- (CHB, D, T) -> (CHB*T, D) transpose ----------
__global__ __launch_bounds__(256) void transpose_k(const float* __restrict__ src, float* __restrict__ dst) {
  __shared__ float tile[32][33];
  const int lb = blockIdx.z;
  const int n0 = blockIdx.y * 32;
  const int t0 = blockIdx.x * 32;
  const int tx = threadIdx.x, ty = threadIdx.y;
#pragma unroll
  for (int r = 0; r < 4; r++)
    tile[ty + r * 8][tx] = src[((size_t)lb * D_ + n0 + ty + r * 8) * T_ + t0 + tx];
  __syncthreads();
#pragma unroll
  for (int r = 0; r < 4; r++)
    dst[((size_t)lb * T_ + t0 + ty + r * 8) * D_ + n0 + tx] = tile[tx][ty + r * 8];
}

// ---------- hamilton + sp_ln + gate + rot + residual + out_ln; updates x planes ----------
template <bool COMP>
__global__ __launch_bounds__(256) void fused_k(const float* __restrict__ inter, const float* __restrict__ Hb,
                                               const float* __restrict__ spw, const float* __restrict__ spb,
                                               const float* __restrict__ gate, const float* __restrict__ rot,
                                               const float* __restrict__ ow, const float* __restrict__ ob,
                                               USHORT* xhi, USHORT* xlo) {
  __shared__ float red[8];
  const int m = blockIdx.x;
  const int d = threadIdx.x;
  const size_t base = (size_t)m * D_;
  float iv[4], hv[4];
#pragma unroll
  for (int k = 0; k < 4; k++) {
    iv[k] = fixf(inter[base + k * 256 + d]);
    hv[k] = fixf(Hb[base + k * 256 + d]);
  }
  float o[4];
  o[0] = iv[0] * hv[0] - iv[1] * hv[1] - iv[2] * hv[2] - iv[3] * hv[3];
  o[1] = iv[0] * hv[1] + iv[1] * hv[0] + iv[2] * hv[3] - iv[3] * hv[2];
  o[2] = iv[0] * hv[2] - iv[1] * hv[3] + iv[2] * hv[0] + iv[3] * hv[1];
  o[3] = iv[0] * hv[3] + iv[1] * hv[2] - iv[2] * hv[1] + iv[3] * hv[0];
  float s = o[0] + o[1] + o[2] + o[3];
  float ss = o[0] * o[0] + o[1] * o[1] + o[2] * o[2] + o[3] * o[3];
  breduce2(s, ss, red);
  const float mean = s * (1.0f / 1024.0f);
  const float rstd = rsqrtf(ss * (1.0f / 1024.0f) - mean * mean + 1e-5f);
  const float g = gate[d];
  float xf[4];
#pragma unroll
  for (int k = 0; k < 4; k++)
    xf[k] = ((o[k] - mean) * rstd * spw[k * 256 + d] + spb[k * 256 + d]) * g;
  float y[4];
#pragma unroll
  for (int j = 0; j < 4; j++) {
    float a = 0.f;
#pragma unroll
    for (int k = 0; k < 4; k++) a += rot[j * 4 + k] * xf[k];
    const size_t idx = base + j * 256 + d;
    float res = b2f(xhi[idx]);
    if (COMP) res += b2f(xlo[idx]);
    y[j] = a + res;  // + residual
  }
  float s2 = y[0] + y[1] + y[2] + y[3];
  float ss2 = y[0] * y[0] + y[1] * y[1] + y[2] * y[2] + y[3] * y[3];
  breduce2(s2, ss2, red);
  const float mean2 = s2 * (1.0f / 1024.0f);
  const float rstd2 = rsqrtf(ss2 * (1.0f / 1024.0f) - mean2 * mean2 + 1e-5f);
#pragma unroll
  for (int j = 0; j < 4; j++) {
    const float v = (y[j] - mean2) * rstd2 * ow[j * 256 + d] + ob[j * 256 + d];
    const size_t idx = base + j * 256 + d;
    const USHORT hh = f2bf(v);
    xhi[idx] = hh;
    if (COMP) xlo[idx] = f2bf(v - b2f(hh));
  }
}

// ---------- mean over T (partials + atomics; pooled must be zeroed) ----------
template <bool COMP>
__global__ __launch_bounds__(256) void pool_k(const USHORT* __restrict__ xhi, const USHORT* __restrict__ xlo,
                                              float* __restrict__ pooled) {
  const int b = blockIdx.z;
  const int d = blockIdx.x * 256 + threadIdx.x;
  const int t0 = blockIdx.y * 256;
  float s = 0.f;
  for (int t = t0; t < t0 + 256; t++) {
    const size_t idx = ((size_t)(b * T_ + t)) * D_ + d;
    s += b2f(xhi[idx]);
    if (COMP) s += b2f(xlo[idx]);
  }
  atomicAdd(&pooled[b * D_ + d], s);
}

// ---------- classifier LN ----------
__global__ __launch_bounds__(256) void clsln_k(const float* __restrict__ pooled, const float* __restrict__ w,
                                               const float* __restrict__ bias, float* __restrict__ h) {
  __shared__ float red[8];
  const int b = blockIdx.x;
  const int d = threadIdx.x;
  float v[4];
#pragma unroll
  for (int j = 0; j < 4; j++) v[j] = fixf(pooled[b * D_ + j * 256 + d]) * (1.0f / (float)T_);
  float s = v[0] + v[1] + v[2] + v[3];
  float ss = v[0] * v[0] + v[1] * v[1] + v[2] * v[2] + v[3] * v[3];
  breduce2(s, ss, red);
  const float mean = s * (1.0f / (float)D_);
  const float rstd = rsqrtf(ss * (1.0f / (float)D_) - mean * mean + 1e-5f);
#pragma unroll
  for (int j = 0; j < 4; j++)
    h[b * D_ + j * 256 + d] = (v[j] - mean) * rstd * w[j * 256 + d] + bias[j * 256 + d];
}

// ---------- classifier GEMM: one wave per (b, n) ----------
__global__ __launch_bounds__(256) void cls_k(const float* __restrict__ h, const float* __restrict__ W,
                                             const float* __restrict__ cb, float* __restrict__ out) {
  const int wv = blockIdx.x * 4 + (threadIdx.x >> 6);
  const int lane = threadIdx.x & 63;
  const int b = wv / NCLS_;
  const int n = wv - b * NCLS_;
  const float* hb = h + b * D_;
  const float* wr = W + (size_t)n * D_;
  float s = 0.f;
  for (int j = lane; j < D_; j += 64) s += hb[j] * wr[j];
#pragma unroll
  for (int off = 32; off > 0; off >>= 1) s += __shfl_down(s, off);
  if (lane == 0) out[b * NCLS_ + n] = fixf(s + cb[n]);
}

// ---------- launch ----------
extern "C" void kernel_launch(void* const* d_in, const int* in_sizes, int n_in,
                              void* d_out, int out_size, void* d_ws, size_t ws_size,
                              hipStream_t stream) {
  (void)in_sizes; (void)n_in; (void)out_size;
  const int* tokens = (const int*)d_in[0];
  const float* emb = (const float*)d_in[1];
  const float* pos = (const float*)d_in[2];
  const float* Wq = (const float*)d_in[3];
  const float* bq = (const float*)d_in[4];
  const float* Wr = (const float*)d_in[5];
  const float* br = (const float*)d_in[6];
  const float* Wh = (const float*)d_in[7];
  const float* bh = (const float*)d_in[8];
  const float* alpha = (const float*)d_in[9];
  const float* spw = (const float*)d_in[10];
  const float* spb = (const float*)d_in[11];
  const float* gate = (const float*)d_in[12];
  const float* rot = (const float*)d_in[13];
  const float* outw = (const float*)d_in[14];
  const float* outb = (const float*)d_in[15];
  const float* clw = (const float*)d_in[16];
  const float* clb = (const float*)d_in[17];
  const float* clsW = (const float*)d_in[18];
  const float* clsb = (const float*)d_in[19];
  float* out = (float*)d_out;

  // ---- adaptive footprint from ws_size ----
  const size_t MB = 1048576;
  int CHB; bool comp;
  if      (ws_size >= 172 * MB) { CHB = 4; comp = true;  }   // 64+12+96
  else if (ws_size >= 124 * MB) { CHB = 2; comp = true;  }   // 64+12+48
  else if (ws_size >= 100 * MB) { CHB = 1; comp = true;  }   // 64+12+24
  else                          { CHB = 1; comp = false; }   // 32+6+24 = 62
  const int nchunks = B_ / CHB;
  const int chm = CHB * T_;
  const size_t chunkf = (size_t)CHB * T_ * D_ * 4;

  char* ws = (char*)d_ws;
  USHORT* xhi = (USHORT*)ws;                                    // 32 MB
  USHORT* xlo = (USHORT*)(ws + 32 * MB);                        // 32 MB (comp only)
  char* wb = ws + (comp ? 64 : 32) * MB;
  USHORT* Whi = (USHORT*)wb;                                    // 6 MB: Q,R,H hi planes
  USHORT* Wlo = (USHORT*)(wb + 6 * MB);                         // 6 MB (comp only)
  char* fb = wb + (comp ? 12 : 6) * MB;
  float* QTc = (float*)fb;
  float* RTc = (float*)(fb + chunkf);
  float* Hc  = (float*)(fb + 2 * chunkf);
  float* pooled = (float*)fb;                                   // reuse after layers
  float* hbuf   = (float*)(fb + 32768);

  if (comp) embed_k<true><<<M_, 256, 0, stream>>>(tokens, emb, pos, xhi, xlo);
  else      embed_k<false><<<M_, 256, 0, stream>>>(tokens, emb, pos, xhi, xlo);

  const int DD = D_ * D_;
  const dim3 gemm_grid(8, chm / 128);
  const dim3 tr_grid(T_ / 32, D_ / 32, CHB);
  const dim3 tr_blk(32, 8);
  for (int l = 0; l < L_; l++) {
    const size_t wo = (size_t)l * DD;
    if (comp) {
      wsplit_k<true><<<DD / 1024, 256, 0, stream>>>(Wq + wo, Whi, Wlo);
      wsplit_k<true><<<DD / 1024, 256, 0, stream>>>(Wr + wo, Whi + DD, Wlo + DD);
      wsplit_k<true><<<DD / 1024, 256, 0, stream>>>(Wh + wo, Whi + 2 * DD, Wlo + 2 * DD);
    } else {
      wsplit_k<false><<<DD / 1024, 256, 0, stream>>>(Wq + wo, Whi, Wlo);
      wsplit_k<false><<<DD / 1024, 256, 0, stream>>>(Wr + wo, Whi + DD, Wlo + DD);
      wsplit_k<false><<<DD / 1024, 256, 0, stream>>>(Wh + wo, Whi + 2 * DD, Wlo + 2 * DD);
    }
    for (int c = 0; c < nchunks; c++) {
      const size_t xoff = (size_t)c * chm * D_;
      const USHORT* xh = xhi + xoff;
      const USHORT* xl = xlo + xoff;
      if (comp) {
        gemm_k<true, true><<<gemm_grid, 256, 0, stream>>>(xh, xl, Whi, Wlo, bq + l * D_, QTc);
        gemm_k<true, true><<<gemm_grid, 256, 0, stream>>>(xh, xl, Whi + DD, Wlo + DD, br + l * D_, RTc);
        gemm_k<false, true><<<gemm_grid, 256, 0, stream>>>(xh, xl, Whi + 2 * DD, Wlo + 2 * DD, bh + l * D_, Hc);
      } else {
        gemm_k<true, false><<<gemm_grid, 256, 0, stream>>>(xh, xh, Whi, Whi, bq + l * D_, QTc);
        gemm_k<true, false><<<gemm_grid, 256, 0, stream>>>(xh, xh, Whi + DD, Whi + DD, br + l * D_, RTc);
        gemm_k<false, false><<<gemm_grid, 256, 0, stream>>>(xh, xh, Whi + 2 * DD, Whi + 2 * DD, bh + l * D_, Hc);
      }
      fft_spectral_k<<<CHB * D_, 256, 0, stream>>>(QTc, RTc, alpha + l * QD_);
      transpose_k<<<tr_grid, tr_blk, 0, stream>>>(QTc, RTc);  // inter -> (chm, D) in RTc
      if (comp)
        fused_k<true><<<chm, 256, 0, stream>>>(RTc, Hc, spw + l * D_, spb + l * D_, gate + l * QD_,
                                               rot + l * 16, outw + l * D_, outb + l * D_,
                                               xhi + xoff, xlo + xoff);
      else
        fused_k<false><<<chm, 256, 0, stream>>>(RTc, Hc, spw + l * D_, spb + l * D_, gate + l * QD_,
                                                rot + l * 16, outw + l * D_, outb + l * D_,
                                                xhi + xoff, xlo + xoff);
    }
  }

  hipMemsetAsync(pooled, 0, B_ * D_ * sizeof(float), stream);
  if (comp) pool_k<true><<<dim3(4, 8, 8), 256, 0, stream>>>(xhi, xlo, pooled);
  else      pool_k<false><<<dim3(4, 8, 8), 256, 0, stream>>>(xhi, xlo, pooled);
  clsln_k<<<B_, 256, 0, stream>>>(pooled, clw, clb, hbuf);
  cls_k<<<(B_ * NCLS_) / 4, 256, 0, stream>>>(hbuf, clsW, clsb, out);
}